// Round 10
// baseline (32886.957 us; speedup 1.0000x reference)
//
#include <hip/hip_runtime.h>
#include <math.h>

// RNNAttentionDecoder on MI355X — round 10: R9 structure + instruction economy.
// Lane re-layout (kl x bq): activation reads become volatile float4 coherent
// loads (global_load_dwordx4 sc0 sc1) along b — 4x fewer VMEM instrs; W LDS
// reads carry 8 distinct bank-disjoint addresses per instr — 4x fewer ds_reads;
// pred Wp broadcast-loads cut ~2.4x. 4 barriers/step, fence-free coherence.
// All f32 (argmax feedback forbids bf16; no fp32 MFMA on CDNA4).

typedef unsigned long long u64;
typedef float v4f __attribute__((ext_vector_type(4)));

#define NS 196
#define ND 512
#define NK 256
#define NV 10000
#define NT 300
#define NBLK 256
#define NTHR 512
#define NPRED 209
#define ATT0 224
#define SCOPE __HIP_MEMORY_SCOPE_AGENT

__device__ __forceinline__ float sigm(float x) { return 1.0f / (1.0f + expf(-x)); }

__device__ __forceinline__ float aldf(const float* p) {
  return __hip_atomic_load(p, __ATOMIC_RELAXED, SCOPE);
}
__device__ __forceinline__ void astf(float* p, float v) {
  __hip_atomic_store(p, v, __ATOMIC_RELAXED, SCOPE);
}
__device__ __forceinline__ u64 aldu(const u64* p) {
  return __hip_atomic_load(p, __ATOMIC_RELAXED, SCOPE);
}
__device__ __forceinline__ void astu(u64* p, u64 v) {
  __hip_atomic_store(p, v, __ATOMIC_RELAXED, SCOPE);
}
// coherent 16B load: volatile -> global_load_dwordx4 sc0=1 sc1=1 (gfx940+)
__device__ __forceinline__ v4f vald4(const float* p) {
  return *(const volatile v4f*)p;
}

__device__ __forceinline__ u64 packmax(float x, int v) {
  unsigned u = __float_as_uint(x);
  u = (u & 0x80000000u) ? ~u : (u | 0x80000000u);
  return ((u64)u << 32) | (u64)(0xFFFFFFFFu - (unsigned)v);
}

__device__ __forceinline__ int eslot(int b, int k4) {
  return b * 32 + ((k4 & ~7) | ((k4 ^ b) & 7));
}

// ---- fence-free hierarchical grid barrier (R6-validated) ----
__device__ __forceinline__ void gbar(unsigned* bar, int bid, unsigned ep, bool fenced) {
  __syncthreads();
  if (threadIdx.x == 0) {
    if (fenced) __threadfence();
    asm volatile("s_waitcnt vmcnt(0)" ::: "memory");
    const int g = bid & 7;
    const unsigned old = __hip_atomic_fetch_add(&bar[g * 32], 1u, __ATOMIC_RELAXED, SCOPE);
    if (old == ep * 32u - 1u) {
      const unsigned r = __hip_atomic_fetch_add(&bar[512], 1u, __ATOMIC_RELAXED, SCOPE);
      if (r == ep * 8u - 1u) {
#pragma unroll
        for (int i = 0; i < 8; ++i)
          __hip_atomic_store(&bar[256 + i * 32], ep, __ATOMIC_RELAXED, SCOPE);
      }
    }
    while (__hip_atomic_load(&bar[256 + g * 32], __ATOMIC_RELAXED, SCOPE) < ep)
      __builtin_amdgcn_s_sleep(1);
    if (fenced) __threadfence();
  }
  __syncthreads();
}

__global__ __launch_bounds__(256) void k_zbar(unsigned* bar) {
  const int i = blockIdx.x * 256 + threadIdx.x;
  if (i < 1024) bar[i] = 0u;
}

struct Params {
  const float *x, *emb, *Wk, *bk, *Wv, *bv, *Wq, *bq, *Wp, *bp;
  const float *Wih0, *Whh0, *bih0, *bhh0, *Wih1, *Whh1, *bih1, *bhh1;
  float *out, *keys, *values, *h0t, *h1t, *c0, *c1, *ctx;
  u64 *amax;
  unsigned *bar;
};

__global__ __launch_bounds__(NTHR, 1) void k_all(Params p) {
  extern __shared__ float dyn[];
  float* W0lds = dyn;                  // [8][1280]: Wih0(768)|Whh0(512) per row
  float* W1lds = dyn + 10240;          // [8][1024]: Wih1(512)|Whh1(512) per row
  float* stage = dyn + 18432;          // [32][32] f4-slots (16 KB)

  __shared__ __align__(16) float arena[2560];
  __shared__ int tok_lds[32];
  __shared__ u64 cand2[32][12];

  const int bid = blockIdx.x;
  const int t = threadIdx.x;
  const int lane = t & 63;
  const int w = t >> 6;

  // ================= init =================
  {
    const int g = bid * NTHR + t;
    if (g < 65536) astf(&p.h0t[g], 0.0f);
    if (g < 8192) astf(&p.ctx[g], 0.0f);
    if (g < 256) astu(&p.amax[g], (g < 32) ? ((1ull << 32) | 0xFFFFFFFFull) : 0ull);
  }
  if (t < 64) {
    const int idx = (bid * 2 + (t >> 5)) * 32 + (t & 31);
    p.c0[idx] = 0.0f;
    p.c1[idx] = 0.0f;
  }
  // ---- pin this block's 8 LSTM gate-rows in LDS (once) ----
  {
    const int r = t >> 6, ln = t & 63;
    const int grow = (r >> 1) * ND + bid * 2 + (r & 1);
    const float* s0i = p.Wih0 + (size_t)grow * 768;
    const float* s0h = p.Whh0 + (size_t)grow * ND;
#pragma unroll
    for (int j = 0; j < 5; ++j) {
      const int col = 4 * (ln + 64 * j);
      const float4 v = (col < 768) ? *(const float4*)(s0i + col)
                                   : *(const float4*)(s0h + (col - 768));
      *(float4*)(W0lds + r * 1280 + col) = v;
    }
    const float* s1i = p.Wih1 + (size_t)grow * ND;
    const float* s1h = p.Whh1 + (size_t)grow * ND;
#pragma unroll
    for (int j = 0; j < 4; ++j) {
      const int col = 4 * (ln + 64 * j);
      const float4 v = (col < 512) ? *(const float4*)(s1i + col)
                                   : *(const float4*)(s1h + (col - 512));
      *(float4*)(W1lds + r * 1024 + col) = v;
    }
  }
  // ---- keys/values (once) ----
  {
    const int kc = bid & 7, bb = bid >> 3;
    const int kl = t & 31, sg = t >> 5;
    const int k = kc * 32 + kl;
    float ak[13], av[13];
#pragma unroll
    for (int i = 0; i < 13; ++i) { ak[i] = 0.f; av[i] = 0.f; }
    const float* wkr = p.Wk + (size_t)k * ND;
    const float* wvr = p.Wv + (size_t)k * ND;
    const float* xb = p.x + (size_t)bb * NS * ND;
    for (int j = 0; j < ND; j += 4) {
      const float4 wk4 = *(const float4*)(wkr + j);
      const float4 wv4 = *(const float4*)(wvr + j);
#pragma unroll
      for (int si = 0; si < 13; ++si) {
        const int s = sg + si * 16;
        if (s < NS) {
          const float4 xv = *(const float4*)(xb + (size_t)s * ND + j);
          ak[si] += wk4.x * xv.x + wk4.y * xv.y + wk4.z * xv.z + wk4.w * xv.w;
          av[si] += wv4.x * xv.x + wv4.y * xv.y + wv4.z * xv.z + wv4.w * xv.w;
        }
      }
    }
    const float bkk = p.bk[k], bvv = p.bv[k];
#pragma unroll
    for (int si = 0; si < 13; ++si) {
      const int s = sg + si * 16;
      if (s < NS) {
        const size_t o = ((size_t)bb * NS + s) * NK + k;
        p.keys[o] = ak[si] + bkk;
        p.values[o] = av[si] + bvv;
      }
    }
  }
  unsigned ep = 1;
  gbar(p.bar, bid, ep++, true);

  // ================= decode loop =================
  for (int step = 0; step < NT; ++step) {
    const int cur = step & 1;
    const float* h0c = p.h0t + cur * 16384;
    float* h0n = p.h0t + (cur ^ 1) * 16384;
    const float* h1c = p.h1t + cur * 16384;
    float* h1n = p.h1t + (cur ^ 1) * 16384;

    // ===== P1: LSTM0 =====
    if (t < 32) {
      u64 m = aldu(&p.amax[t]);
#pragma unroll
      for (int s2 = 1; s2 < 8; ++s2) { const u64 o = aldu(&p.amax[s2 * 32 + t]); if (o > m) m = o; }
      tok_lds[t] = (int)(0xFFFFFFFFu - (unsigned)(m & 0xFFFFFFFFull));
    }
    __syncthreads();
    // --- emb part (R9 lanes: b=lane&31, kq=lane>>5; wave=(rq2, ks4)) ---
    {
      const int rq = w >> 2, ks = w & 3;
      const int b = lane & 31, kq = lane >> 5;
      const int rb = rq * 4;
      float a0 = 0.f, a1 = 0.f, a2 = 0.f, a3 = 0.f;
      for (int c = 0; c < 4; ++c) {
        {
          const int eb = t >> 4, sl = t & 15;
          const float* er = p.emb + (size_t)tok_lds[eb] * ND + c * 128;
          *(float4*)(stage + 4 * eslot(eb, sl)) = *(const float4*)(er + 4 * sl);
          *(float4*)(stage + 4 * eslot(eb, sl + 16)) = *(const float4*)(er + 4 * (sl + 16));
        }
        __syncthreads();
#pragma unroll
        for (int jj = 0; jj < 4; ++jj) {
          const int f4 = ks * 8 + kq * 4 + jj;
          const float4 a4 = *(const float4*)(stage + 4 * eslot(b, f4));
          const int wc = c * 128 + 4 * f4;
          const float4 q0 = *(const float4*)(W0lds + (rb + 0) * 1280 + wc);
          const float4 q1 = *(const float4*)(W0lds + (rb + 1) * 1280 + wc);
          const float4 q2 = *(const float4*)(W0lds + (rb + 2) * 1280 + wc);
          const float4 q3 = *(const float4*)(W0lds + (rb + 3) * 1280 + wc);
          a0 += q0.x * a4.x + q0.y * a4.y + q0.z * a4.z + q0.w * a4.w;
          a1 += q1.x * a4.x + q1.y * a4.y + q1.z * a4.z + q1.w * a4.w;
          a2 += q2.x * a4.x + q2.y * a4.y + q2.z * a4.z + q2.w * a4.w;
          a3 += q3.x * a4.x + q3.y * a4.y + q3.z * a4.z + q3.w * a4.w;
        }
        __syncthreads();
      }
      a0 += __shfl_xor(a0, 32);
      a1 += __shfl_xor(a1, 32);
      a2 += __shfl_xor(a2, 32);
      a3 += __shfl_xor(a3, 32);
      if (kq == 0) {
        arena[(ks * 8 + rb + 0) * 32 + b] = a0;
        arena[(ks * 8 + rb + 1) * 32 + b] = a1;
        arena[(ks * 8 + rb + 2) * 32 + b] = a2;
        arena[(ks * 8 + rb + 3) * 32 + b] = a3;
      }
    }
    // --- ctx/h0 part (new lanes: bq=lane&7, kl=lane>>3; wave=(rq4, kh2)) ---
    {
      const int rq4 = w >> 1, kh = w & 1;
      const int bq = lane & 7, kl = lane >> 3;
      const int r0 = rq4 * 2, r1 = r0 + 1;
      const float* wr0 = W0lds + r0 * 1280 + 512 + kh * 384 + kl * 4;
      const float* wr1 = W0lds + r1 * 1280 + 512 + kh * 384 + kl * 4;
      v4f ac0 = {0.f, 0.f, 0.f, 0.f}, ac1 = {0.f, 0.f, 0.f, 0.f};
#pragma unroll 3
      for (int j = 0; j < 12; ++j) {
        const int kk = kh * 384 + j * 32 + kl * 4;   // concat-local k (uniform src per j)
        const float* asrc = (kk < 256) ? (p.ctx + (size_t)kk * 32)
                                       : (h0c + (size_t)(kk - 256) * 32);
        const v4f x0 = vald4(asrc + 0 * 32 + bq * 4);
        const v4f x1 = vald4(asrc + 1 * 32 + bq * 4);
        const v4f x2 = vald4(asrc + 2 * 32 + bq * 4);
        const v4f x3 = vald4(asrc + 3 * 32 + bq * 4);
        const v4f q0 = *(const v4f*)(wr0 + j * 32);
        const v4f q1 = *(const v4f*)(wr1 + j * 32);
        ac0 += q0[0] * x0 + q0[1] * x1 + q0[2] * x2 + q0[3] * x3;
        ac1 += q1[0] * x0 + q1[1] * x1 + q1[2] * x2 + q1[3] * x3;
      }
#pragma unroll
      for (int c = 0; c < 4; ++c) {
        float v0 = ac0[c], v1 = ac1[c];
        v0 += __shfl_xor(v0, 8);  v1 += __shfl_xor(v1, 8);
        v0 += __shfl_xor(v0, 16); v1 += __shfl_xor(v1, 16);
        v0 += __shfl_xor(v0, 32); v1 += __shfl_xor(v1, 32);
        ac0[c] = v0; ac1[c] = v1;
      }
      if (kl == 0) {
#pragma unroll
        for (int i = 0; i < 4; ++i) {
          arena[1024 + (kh * 8 + r0) * 32 + bq * 4 + i] = ac0[i];
          arena[1024 + (kh * 8 + r1) * 32 + bq * 4 + i] = ac1[i];
        }
      }
    }
    __syncthreads();
    if (t < 256) {
      const int r = t >> 5, b2 = t & 31;
      const int grow = (r >> 1) * ND + bid * 2 + (r & 1);
      arena[1536 + r * 32 + b2] =
          arena[(0 * 8 + r) * 32 + b2] + arena[(1 * 8 + r) * 32 + b2]
        + arena[(2 * 8 + r) * 32 + b2] + arena[(3 * 8 + r) * 32 + b2]
        + arena[1024 + (0 * 8 + r) * 32 + b2] + arena[1024 + (1 * 8 + r) * 32 + b2]
        + p.bih0[grow] + p.bhh0[grow];
    }
    __syncthreads();
    if (t < 64) {
      const int dl = t >> 5, b2 = t & 31;
      const int idx = (bid * 2 + dl) * 32 + b2;
      const float gi = arena[1536 + (0 + dl) * 32 + b2], gf = arena[1536 + (2 + dl) * 32 + b2];
      const float gg = arena[1536 + (4 + dl) * 32 + b2], go = arena[1536 + (6 + dl) * 32 + b2];
      const float cn = sigm(gf) * p.c0[idx] + sigm(gi) * tanhf(gg);
      p.c0[idx] = cn;
      astf(&h0n[idx], sigm(go) * tanhf(cn));
    }
    gbar(p.bar, bid, ep++, false);

    // ===== P2: LSTM1 (new lanes) + amax reset =====
    if (bid == 0 && t < 256) astu(&p.amax[t], 0ull);
    {
      const int rq4 = w >> 1, kh = w & 1;
      const int bq = lane & 7, kl = lane >> 3;
      const int r0 = rq4 * 2, r1 = r0 + 1;
      const float* wr0 = W1lds + r0 * 1024 + kh * 512 + kl * 4;
      const float* wr1 = W1lds + r1 * 1024 + kh * 512 + kl * 4;
      const float* abase = (kh == 0) ? h0n : h1c;
      v4f ac0 = {0.f, 0.f, 0.f, 0.f}, ac1 = {0.f, 0.f, 0.f, 0.f};
#pragma unroll 4
      for (int j = 0; j < 16; ++j) {
        const float* asrc = abase + (size_t)(j * 32 + kl * 4) * 32;
        const v4f x0 = vald4(asrc + 0 * 32 + bq * 4);
        const v4f x1 = vald4(asrc + 1 * 32 + bq * 4);
        const v4f x2 = vald4(asrc + 2 * 32 + bq * 4);
        const v4f x3 = vald4(asrc + 3 * 32 + bq * 4);
        const v4f q0 = *(const v4f*)(wr0 + j * 32);
        const v4f q1 = *(const v4f*)(wr1 + j * 32);
        ac0 += q0[0] * x0 + q0[1] * x1 + q0[2] * x2 + q0[3] * x3;
        ac1 += q1[0] * x0 + q1[1] * x1 + q1[2] * x2 + q1[3] * x3;
      }
#pragma unroll
      for (int c = 0; c < 4; ++c) {
        float v0 = ac0[c], v1 = ac1[c];
        v0 += __shfl_xor(v0, 8);  v1 += __shfl_xor(v1, 8);
        v0 += __shfl_xor(v0, 16); v1 += __shfl_xor(v1, 16);
        v0 += __shfl_xor(v0, 32); v1 += __shfl_xor(v1, 32);
        ac0[c] = v0; ac1[c] = v1;
      }
      if (kl == 0) {
#pragma unroll
        for (int i = 0; i < 4; ++i) {
          arena[(kh * 8 + r0) * 32 + bq * 4 + i] = ac0[i];
          arena[(kh * 8 + r1) * 32 + bq * 4 + i] = ac1[i];
        }
      }
    }
    __syncthreads();
    if (t < 256) {
      const int r = t >> 5, b2 = t & 31;
      const int grow = (r >> 1) * ND + bid * 2 + (r & 1);
      arena[512 + r * 32 + b2] =
          arena[(0 * 8 + r) * 32 + b2] + arena[(1 * 8 + r) * 32 + b2]
        + p.bih1[grow] + p.bhh1[grow];
    }
    __syncthreads();
    if (t < 64) {
      const int dl = t >> 5, b2 = t & 31;
      const int idx = (bid * 2 + dl) * 32 + b2;
      const float gi = arena[512 + (0 + dl) * 32 + b2], gf = arena[512 + (2 + dl) * 32 + b2];
      const float gg = arena[512 + (4 + dl) * 32 + b2], go = arena[512 + (6 + dl) * 32 + b2];
      const float cn = sigm(gf) * p.c1[idx] + sigm(gi) * tanhf(gg);
      p.c1[idx] = cn;
      astf(&h1n[idx], sigm(go) * tanhf(cn));
    }
    gbar(p.bar, bid, ep++, false);

    // ===== P3: attention (blocks 224..255) ∥ pred-h1 (blocks 0..208) =====
    v4f pa[6];
#pragma unroll
    for (int r = 0; r < 6; ++r) pa[r] = (v4f){0.f, 0.f, 0.f, 0.f};
    if (bid >= ATT0) {
      const int b = bid - ATT0;
      float* hb  = arena;
      float* qs  = arena + 512;
      float* red = arena + 768;
      float* smx = arena + 1024;
      hb[t] = aldf(h1n + t * 32 + b);
      __syncthreads();
      const int kl = lane & 31, rh = lane >> 5;
      for (int pp = 0; pp < 16; ++pp) {
        const int r = w * 32 + pp * 2 + rh;
        const float* wq = p.Wq + (size_t)r * ND + kl * 4;
        float a = 0.f;
#pragma unroll
        for (int i = 0; i < 4; ++i) {
          const float4 w4 = *(const float4*)(wq + i * 128);
          const float4 h4 = *(const float4*)(hb + i * 128 + kl * 4);
          a += w4.x * h4.x + w4.y * h4.y + w4.z * h4.z + w4.w * h4.w;
        }
#pragma unroll
        for (int mk = 1; mk < 32; mk <<= 1) a += __shfl_xor(a, mk);
        if (kl == 0) qs[r] = (a + p.bq[r]) * 0.0625f;
      }
      __syncthreads();
      for (int pp = 0; pp < 13; ++pp) {
        const int s = pp * 16 + w * 2 + rh;
        float a = 0.f;
        if (s < NS) {
          const float* kr = p.keys + ((size_t)b * NS + s) * NK + kl * 4;
#pragma unroll
          for (int i = 0; i < 2; ++i) {
            const float4 k4 = *(const float4*)(kr + i * 128);
            const float4 q4 = *(const float4*)(qs + i * 128 + kl * 4);
            a += k4.x * q4.x + k4.y * q4.y + k4.z * q4.z + k4.w * q4.w;
          }
        }
#pragma unroll
        for (int mk = 1; mk < 32; mk <<= 1) a += __shfl_xor(a, mk);
        if (kl == 0 && s < NS) smx[s] = a;
      }
      __syncthreads();
      float e = -INFINITY;
      if (t < 256) { e = (t < NS) ? smx[t] : -INFINITY; red[t] = e; }
      __syncthreads();
      for (int off = 128; off; off >>= 1) {
        if (t < off) red[t] = fmaxf(red[t], red[t + off]);
        __syncthreads();
      }
      const float mx = red[0];
      __syncthreads();
      float a = 0.f;
      if (t < 256) { a = (t < NS) ? expf(e - mx) : 0.f; red[t] = a; }
      __syncthreads();
      for (int off = 128; off; off >>= 1) {
        if (t < off) red[t] += red[t + off];
        __syncthreads();
      }
      const float inv = 1.0f / red[0];
      if (t < 256) smx[t] = a * inv;
      __syncthreads();
      if (t < 256) {
        const float* vb = p.values + (size_t)b * NS * NK + t;
        float c0_ = 0.f, c1_ = 0.f, c2_ = 0.f, c3_ = 0.f;
        for (int s = 0; s < NS; s += 4) {
          c0_ += smx[s + 0] * vb[(size_t)(s + 0) * NK];
          c1_ += smx[s + 1] * vb[(size_t)(s + 1) * NK];
          c2_ += smx[s + 2] * vb[(size_t)(s + 2) * NK];
          c3_ += smx[s + 3] * vb[(size_t)(s + 3) * NK];
        }
        astf(&p.ctx[t * 32 + b], (c0_ + c1_) + (c2_ + c3_));
      }
    } else if (bid < NPRED) {
      const int bq = lane & 7, kl = lane >> 3;
      const int rbase = bid * 48 + w * 6;
      int rc[6];
#pragma unroll
      for (int r = 0; r < 6; ++r) rc[r] = (rbase + r < NV) ? (rbase + r) : (NV - 1);
#pragma unroll 2
      for (int j = 0; j < 16; ++j) {
        const int kk = j * 32 + kl * 4;
        const float* asrc = h1n + (size_t)kk * 32;
        const v4f x0 = vald4(asrc + 0 * 32 + bq * 4);
        const v4f x1 = vald4(asrc + 1 * 32 + bq * 4);
        const v4f x2 = vald4(asrc + 2 * 32 + bq * 4);
        const v4f x3 = vald4(asrc + 3 * 32 + bq * 4);
#pragma unroll
        for (int r = 0; r < 6; ++r) {
          const v4f q = *(const v4f*)(p.Wp + (size_t)rc[r] * 768 + kk);
          pa[r] += q[0] * x0 + q[1] * x1 + q[2] * x2 + q[3] * x3;
        }
      }
    }
    gbar(p.bar, bid, ep++, false);

    // ===== P4: pred-ctx part + reduce + out + argmax =====
    if (bid < NPRED) {
      const int bq = lane & 7, kl = lane >> 3;
      const int rbase = bid * 48 + w * 6;
      int rc[6];
#pragma unroll
      for (int r = 0; r < 6; ++r) rc[r] = (rbase + r < NV) ? (rbase + r) : (NV - 1);
#pragma unroll 2
      for (int j = 0; j < 8; ++j) {
        const int kk = j * 32 + kl * 4;
        const float* asrc = p.ctx + (size_t)kk * 32;
        const v4f x0 = vald4(asrc + 0 * 32 + bq * 4);
        const v4f x1 = vald4(asrc + 1 * 32 + bq * 4);
        const v4f x2 = vald4(asrc + 2 * 32 + bq * 4);
        const v4f x3 = vald4(asrc + 3 * 32 + bq * 4);
#pragma unroll
        for (int r = 0; r < 6; ++r) {
          const v4f q = *(const v4f*)(p.Wp + (size_t)rc[r] * 768 + 512 + kk);
          pa[r] += q[0] * x0 + q[1] * x1 + q[2] * x2 + q[3] * x3;
        }
      }
#pragma unroll
      for (int r = 0; r < 6; ++r) {
#pragma unroll
        for (int c = 0; c < 4; ++c) {
          float v = pa[r][c];
          v += __shfl_xor(v, 8);
          v += __shfl_xor(v, 16);
          v += __shfl_xor(v, 32);
          pa[r][c] = v;
        }
      }
      if (kl == 0) {
#pragma unroll
        for (int r = 0; r < 6; ++r)
#pragma unroll
          for (int i = 0; i < 4; ++i)
            arena[(w * 6 + r) * 32 + bq * 4 + i] = pa[r][i];
      }
      __syncthreads();
      if (t < 384) {
        const int b2 = t & 31, rg = t >> 5;
        const int vb = bid * 48 + rg * 4;
        u64 m = 0ull;
        if (vb + 3 < NV) {
          float4 v;
          float* vp = &v.x;
#pragma unroll
          for (int i = 0; i < 4; ++i) {
            const int row = rg * 4 + i;
            vp[i] = arena[row * 32 + b2] + p.bp[vb + i];
          }
          *(float4*)(p.out + ((size_t)b2 * NT + step) * NV + vb) = v;
          m = packmax(v.x, vb + 0);
          const u64 o1 = packmax(v.y, vb + 1); if (o1 > m) m = o1;
          const u64 o2 = packmax(v.z, vb + 2); if (o2 > m) m = o2;
          const u64 o3 = packmax(v.w, vb + 3); if (o3 > m) m = o3;
        }
        cand2[b2][rg] = m;
      }
      __syncthreads();
      if (t < 32) {
        u64 mm = cand2[t][0];
#pragma unroll
        for (int i = 1; i < 12; ++i) { const u64 o = cand2[t][i]; if (o > mm) mm = o; }
        (void)__hip_atomic_fetch_max(&p.amax[(bid & 7) * 32 + t], mm, __ATOMIC_RELAXED, SCOPE);
      }
    }
    gbar(p.bar, bid, ep++, false);
  }
}

// ---------------- host ----------------
extern "C" void kernel_launch(void* const* d_in, const int* in_sizes, int n_in,
                              void* d_out, int out_size, void* d_ws, size_t ws_size,
                              hipStream_t stream) {
  (void)in_sizes; (void)n_in; (void)out_size; (void)ws_size;
  Params prm;
  prm.x    = (const float*)d_in[0];
  prm.emb  = (const float*)d_in[1];
  prm.Wk   = (const float*)d_in[2];
  prm.bk   = (const float*)d_in[3];
  prm.Wv   = (const float*)d_in[4];
  prm.bv   = (const float*)d_in[5];
  prm.Wq   = (const float*)d_in[6];
  prm.bq   = (const float*)d_in[7];
  prm.Wp   = (const float*)d_in[8];
  prm.bp   = (const float*)d_in[9];
  prm.Wih0 = (const float*)d_in[10];
  prm.Whh0 = (const float*)d_in[11];
  prm.bih0 = (const float*)d_in[12];
  prm.bhh0 = (const float*)d_in[13];
  prm.Wih1 = (const float*)d_in[14];
  prm.Whh1 = (const float*)d_in[15];
  prm.bih1 = (const float*)d_in[16];
  prm.bhh1 = (const float*)d_in[17];
  prm.out  = (float*)d_out;

  float* ws = (float*)d_ws;
  prm.keys   = ws;
  prm.values = prm.keys + 1605632;
  prm.h0t    = prm.values + 1605632;
  prm.h1t    = prm.h0t + 32768;
  prm.c0     = prm.h1t + 32768;
  prm.c1     = prm.c0 + 16384;
  prm.ctx    = prm.c1 + 16384;
  prm.amax   = (u64*)(prm.ctx + 8192);
  prm.bar    = (unsigned*)(prm.amax + 256);

  const int LDS = (10240 + 8192 + 4096) * 4;  // 90,112 B dynamic
  (void)hipFuncSetAttribute((const void*)k_all, hipFuncAttributeMaxDynamicSharedMemorySize, LDS);

  k_zbar<<<4, 256, 0, stream>>>(prm.bar);
  void* args[] = { &prm };
  (void)hipLaunchCooperativeKernel((const void*)k_all, dim3(NBLK), dim3(NTHR), args,
                                   (unsigned)LDS, stream);
}

// Round 11
// 24680.392 us; speedup vs baseline: 1.3325x; 1.3325x over previous
//
#include <hip/hip_runtime.h>
#include <math.h>

// RNNAttentionDecoder on MI355X — round 11: R10 structure, but activation reads
// via PAIRED 8-byte relaxed AGENT atomic loads (global_load_dwordx2 sc0 —
// L2-served) instead of volatile sc0+sc1 (which bypassed L2 -> R10 regression).
// 2x instruction economy over R9 scalar atomics at R9's load latency.
// All f32 (argmax feedback forbids bf16; no fp32 MFMA on CDNA4).

typedef unsigned long long u64;
typedef float v4f __attribute__((ext_vector_type(4)));

#define NS 196
#define ND 512
#define NK 256
#define NV 10000
#define NT 300
#define NBLK 256
#define NTHR 512
#define NPRED 209
#define ATT0 224
#define SCOPE __HIP_MEMORY_SCOPE_AGENT

__device__ __forceinline__ float sigm(float x) { return 1.0f / (1.0f + expf(-x)); }

__device__ __forceinline__ float aldf(const float* p) {
  return __hip_atomic_load(p, __ATOMIC_RELAXED, SCOPE);
}
__device__ __forceinline__ void astf(float* p, float v) {
  __hip_atomic_store(p, v, __ATOMIC_RELAXED, SCOPE);
}
__device__ __forceinline__ u64 aldu(const u64* p) {
  return __hip_atomic_load(p, __ATOMIC_RELAXED, SCOPE);
}
__device__ __forceinline__ void astu(u64* p, u64 v) {
  __hip_atomic_store(p, v, __ATOMIC_RELAXED, SCOPE);
}
// 16B coherent-enough load: two relaxed AGENT 8B atomic loads (L2-served, sc0)
__device__ __forceinline__ v4f ald16(const float* p) {
  union { u64 q[2]; v4f v; } u;
  u.q[0] = __hip_atomic_load((const u64*)p + 0, __ATOMIC_RELAXED, SCOPE);
  u.q[1] = __hip_atomic_load((const u64*)p + 1, __ATOMIC_RELAXED, SCOPE);
  return u.v;
}

__device__ __forceinline__ u64 packmax(float x, int v) {
  unsigned u = __float_as_uint(x);
  u = (u & 0x80000000u) ? ~u : (u | 0x80000000u);
  return ((u64)u << 32) | (u64)(0xFFFFFFFFu - (unsigned)v);
}

__device__ __forceinline__ int eslot(int b, int k4) {
  return b * 32 + ((k4 & ~7) | ((k4 ^ b) & 7));
}

// ---- fence-free hierarchical grid barrier (R6-validated) ----
__device__ __forceinline__ void gbar(unsigned* bar, int bid, unsigned ep, bool fenced) {
  __syncthreads();
  if (threadIdx.x == 0) {
    if (fenced) __threadfence();
    asm volatile("s_waitcnt vmcnt(0)" ::: "memory");
    const int g = bid & 7;
    const unsigned old = __hip_atomic_fetch_add(&bar[g * 32], 1u, __ATOMIC_RELAXED, SCOPE);
    if (old == ep * 32u - 1u) {
      const unsigned r = __hip_atomic_fetch_add(&bar[512], 1u, __ATOMIC_RELAXED, SCOPE);
      if (r == ep * 8u - 1u) {
#pragma unroll
        for (int i = 0; i < 8; ++i)
          __hip_atomic_store(&bar[256 + i * 32], ep, __ATOMIC_RELAXED, SCOPE);
      }
    }
    while (__hip_atomic_load(&bar[256 + g * 32], __ATOMIC_RELAXED, SCOPE) < ep)
      __builtin_amdgcn_s_sleep(1);
    if (fenced) __threadfence();
  }
  __syncthreads();
}

__global__ __launch_bounds__(256) void k_zbar(unsigned* bar) {
  const int i = blockIdx.x * 256 + threadIdx.x;
  if (i < 1024) bar[i] = 0u;
}

struct Params {
  const float *x, *emb, *Wk, *bk, *Wv, *bv, *Wq, *bq, *Wp, *bp;
  const float *Wih0, *Whh0, *bih0, *bhh0, *Wih1, *Whh1, *bih1, *bhh1;
  float *out, *keys, *values, *h0t, *h1t, *c0, *c1, *ctx;
  u64 *amax;
  unsigned *bar;
};

__global__ __launch_bounds__(NTHR, 1) void k_all(Params p) {
  extern __shared__ float dyn[];
  float* W0lds = dyn;                  // [8][1280]: Wih0(768)|Whh0(512) per row
  float* W1lds = dyn + 10240;          // [8][1024]: Wih1(512)|Whh1(512) per row
  float* stage = dyn + 18432;          // [32][32] f4-slots (16 KB)

  __shared__ __align__(16) float arena[2560];
  __shared__ int tok_lds[32];
  __shared__ u64 cand2[32][12];

  const int bid = blockIdx.x;
  const int t = threadIdx.x;
  const int lane = t & 63;
  const int w = t >> 6;

  // ================= init =================
  {
    const int g = bid * NTHR + t;
    if (g < 65536) astf(&p.h0t[g], 0.0f);
    if (g < 8192) astf(&p.ctx[g], 0.0f);
    if (g < 256) astu(&p.amax[g], (g < 32) ? ((1ull << 32) | 0xFFFFFFFFull) : 0ull);
  }
  if (t < 64) {
    const int idx = (bid * 2 + (t >> 5)) * 32 + (t & 31);
    p.c0[idx] = 0.0f;
    p.c1[idx] = 0.0f;
  }
  // ---- pin this block's 8 LSTM gate-rows in LDS (once) ----
  {
    const int r = t >> 6, ln = t & 63;
    const int grow = (r >> 1) * ND + bid * 2 + (r & 1);
    const float* s0i = p.Wih0 + (size_t)grow * 768;
    const float* s0h = p.Whh0 + (size_t)grow * ND;
#pragma unroll
    for (int j = 0; j < 5; ++j) {
      const int col = 4 * (ln + 64 * j);
      const float4 v = (col < 768) ? *(const float4*)(s0i + col)
                                   : *(const float4*)(s0h + (col - 768));
      *(float4*)(W0lds + r * 1280 + col) = v;
    }
    const float* s1i = p.Wih1 + (size_t)grow * ND;
    const float* s1h = p.Whh1 + (size_t)grow * ND;
#pragma unroll
    for (int j = 0; j < 4; ++j) {
      const int col = 4 * (ln + 64 * j);
      const float4 v = (col < 512) ? *(const float4*)(s1i + col)
                                   : *(const float4*)(s1h + (col - 512));
      *(float4*)(W1lds + r * 1024 + col) = v;
    }
  }
  // ---- keys/values (once) ----
  {
    const int kc = bid & 7, bb = bid >> 3;
    const int kl = t & 31, sg = t >> 5;
    const int k = kc * 32 + kl;
    float ak[13], av[13];
#pragma unroll
    for (int i = 0; i < 13; ++i) { ak[i] = 0.f; av[i] = 0.f; }
    const float* wkr = p.Wk + (size_t)k * ND;
    const float* wvr = p.Wv + (size_t)k * ND;
    const float* xb = p.x + (size_t)bb * NS * ND;
    for (int j = 0; j < ND; j += 4) {
      const float4 wk4 = *(const float4*)(wkr + j);
      const float4 wv4 = *(const float4*)(wvr + j);
#pragma unroll
      for (int si = 0; si < 13; ++si) {
        const int s = sg + si * 16;
        if (s < NS) {
          const float4 xv = *(const float4*)(xb + (size_t)s * ND + j);
          ak[si] += wk4.x * xv.x + wk4.y * xv.y + wk4.z * xv.z + wk4.w * xv.w;
          av[si] += wv4.x * xv.x + wv4.y * xv.y + wv4.z * xv.z + wv4.w * xv.w;
        }
      }
    }
    const float bkk = p.bk[k], bvv = p.bv[k];
#pragma unroll
    for (int si = 0; si < 13; ++si) {
      const int s = sg + si * 16;
      if (s < NS) {
        const size_t o = ((size_t)bb * NS + s) * NK + k;
        p.keys[o] = ak[si] + bkk;
        p.values[o] = av[si] + bvv;
      }
    }
  }
  unsigned ep = 1;
  gbar(p.bar, bid, ep++, true);

  // ================= decode loop =================
  for (int step = 0; step < NT; ++step) {
    const int cur = step & 1;
    const float* h0c = p.h0t + cur * 16384;
    float* h0n = p.h0t + (cur ^ 1) * 16384;
    const float* h1c = p.h1t + cur * 16384;
    float* h1n = p.h1t + (cur ^ 1) * 16384;

    // ===== P1: LSTM0 =====
    if (t < 32) {
      u64 m = aldu(&p.amax[t]);
#pragma unroll
      for (int s2 = 1; s2 < 8; ++s2) { const u64 o = aldu(&p.amax[s2 * 32 + t]); if (o > m) m = o; }
      tok_lds[t] = (int)(0xFFFFFFFFu - (unsigned)(m & 0xFFFFFFFFull));
    }
    __syncthreads();
    // --- emb part (staged; lanes b=lane&31, kq=lane>>5; wave=(rq2, ks4)) ---
    {
      const int rq = w >> 2, ks = w & 3;
      const int b = lane & 31, kq = lane >> 5;
      const int rb = rq * 4;
      float a0 = 0.f, a1 = 0.f, a2 = 0.f, a3 = 0.f;
      for (int c = 0; c < 4; ++c) {
        {
          const int eb = t >> 4, sl = t & 15;
          const float* er = p.emb + (size_t)tok_lds[eb] * ND + c * 128;
          *(float4*)(stage + 4 * eslot(eb, sl)) = *(const float4*)(er + 4 * sl);
          *(float4*)(stage + 4 * eslot(eb, sl + 16)) = *(const float4*)(er + 4 * (sl + 16));
        }
        __syncthreads();
#pragma unroll
        for (int jj = 0; jj < 4; ++jj) {
          const int f4 = ks * 8 + kq * 4 + jj;
          const float4 a4 = *(const float4*)(stage + 4 * eslot(b, f4));
          const int wc = c * 128 + 4 * f4;
          const float4 q0 = *(const float4*)(W0lds + (rb + 0) * 1280 + wc);
          const float4 q1 = *(const float4*)(W0lds + (rb + 1) * 1280 + wc);
          const float4 q2 = *(const float4*)(W0lds + (rb + 2) * 1280 + wc);
          const float4 q3 = *(const float4*)(W0lds + (rb + 3) * 1280 + wc);
          a0 += q0.x * a4.x + q0.y * a4.y + q0.z * a4.z + q0.w * a4.w;
          a1 += q1.x * a4.x + q1.y * a4.y + q1.z * a4.z + q1.w * a4.w;
          a2 += q2.x * a4.x + q2.y * a4.y + q2.z * a4.z + q2.w * a4.w;
          a3 += q3.x * a4.x + q3.y * a4.y + q3.z * a4.z + q3.w * a4.w;
        }
        __syncthreads();
      }
      a0 += __shfl_xor(a0, 32);
      a1 += __shfl_xor(a1, 32);
      a2 += __shfl_xor(a2, 32);
      a3 += __shfl_xor(a3, 32);
      if (kq == 0) {
        arena[(ks * 8 + rb + 0) * 32 + b] = a0;
        arena[(ks * 8 + rb + 1) * 32 + b] = a1;
        arena[(ks * 8 + rb + 2) * 32 + b] = a2;
        arena[(ks * 8 + rb + 3) * 32 + b] = a3;
      }
    }
    // --- ctx/h0 part (lanes: bq=lane&7, kl=lane>>3; wave=(rq4, kh2)) ---
    {
      const int rq4 = w >> 1, kh = w & 1;
      const int bq = lane & 7, kl = lane >> 3;
      const int r0 = rq4 * 2, r1 = r0 + 1;
      const float* wr0 = W0lds + r0 * 1280 + 512 + kh * 384 + kl * 4;
      const float* wr1 = W0lds + r1 * 1280 + 512 + kh * 384 + kl * 4;
      v4f ac0 = {0.f, 0.f, 0.f, 0.f}, ac1 = {0.f, 0.f, 0.f, 0.f};
#pragma unroll 3
      for (int j = 0; j < 12; ++j) {
        const int kk = kh * 384 + j * 32 + kl * 4;   // uniform src side per (kh,j)
        const float* asrc = (kk < 256) ? (p.ctx + (size_t)kk * 32)
                                       : (h0c + (size_t)(kk - 256) * 32);
        const v4f x0 = ald16(asrc + 0 * 32 + bq * 4);
        const v4f x1 = ald16(asrc + 1 * 32 + bq * 4);
        const v4f x2 = ald16(asrc + 2 * 32 + bq * 4);
        const v4f x3 = ald16(asrc + 3 * 32 + bq * 4);
        const v4f q0 = *(const v4f*)(wr0 + j * 32);
        const v4f q1 = *(const v4f*)(wr1 + j * 32);
        ac0 += q0[0] * x0 + q0[1] * x1 + q0[2] * x2 + q0[3] * x3;
        ac1 += q1[0] * x0 + q1[1] * x1 + q1[2] * x2 + q1[3] * x3;
      }
#pragma unroll
      for (int c = 0; c < 4; ++c) {
        float v0 = ac0[c], v1 = ac1[c];
        v0 += __shfl_xor(v0, 8);  v1 += __shfl_xor(v1, 8);
        v0 += __shfl_xor(v0, 16); v1 += __shfl_xor(v1, 16);
        v0 += __shfl_xor(v0, 32); v1 += __shfl_xor(v1, 32);
        ac0[c] = v0; ac1[c] = v1;
      }
      if (kl == 0) {
#pragma unroll
        for (int i = 0; i < 4; ++i) {
          arena[1024 + (kh * 8 + r0) * 32 + bq * 4 + i] = ac0[i];
          arena[1024 + (kh * 8 + r1) * 32 + bq * 4 + i] = ac1[i];
        }
      }
    }
    __syncthreads();
    if (t < 256) {
      const int r = t >> 5, b2 = t & 31;
      const int grow = (r >> 1) * ND + bid * 2 + (r & 1);
      arena[1536 + r * 32 + b2] =
          arena[(0 * 8 + r) * 32 + b2] + arena[(1 * 8 + r) * 32 + b2]
        + arena[(2 * 8 + r) * 32 + b2] + arena[(3 * 8 + r) * 32 + b2]
        + arena[1024 + (0 * 8 + r) * 32 + b2] + arena[1024 + (1 * 8 + r) * 32 + b2]
        + p.bih0[grow] + p.bhh0[grow];
    }
    __syncthreads();
    if (t < 64) {
      const int dl = t >> 5, b2 = t & 31;
      const int idx = (bid * 2 + dl) * 32 + b2;
      const float gi = arena[1536 + (0 + dl) * 32 + b2], gf = arena[1536 + (2 + dl) * 32 + b2];
      const float gg = arena[1536 + (4 + dl) * 32 + b2], go = arena[1536 + (6 + dl) * 32 + b2];
      const float cn = sigm(gf) * p.c0[idx] + sigm(gi) * tanhf(gg);
      p.c0[idx] = cn;
      astf(&h0n[idx], sigm(go) * tanhf(cn));
    }
    gbar(p.bar, bid, ep++, false);

    // ===== P2: LSTM1 + amax reset =====
    if (bid == 0 && t < 256) astu(&p.amax[t], 0ull);
    {
      const int rq4 = w >> 1, kh = w & 1;
      const int bq = lane & 7, kl = lane >> 3;
      const int r0 = rq4 * 2, r1 = r0 + 1;
      const float* wr0 = W1lds + r0 * 1024 + kh * 512 + kl * 4;
      const float* wr1 = W1lds + r1 * 1024 + kh * 512 + kl * 4;
      const float* abase = (kh == 0) ? h0n : h1c;
      v4f ac0 = {0.f, 0.f, 0.f, 0.f}, ac1 = {0.f, 0.f, 0.f, 0.f};
#pragma unroll 4
      for (int j = 0; j < 16; ++j) {
        const float* asrc = abase + (size_t)(j * 32 + kl * 4) * 32;
        const v4f x0 = ald16(asrc + 0 * 32 + bq * 4);
        const v4f x1 = ald16(asrc + 1 * 32 + bq * 4);
        const v4f x2 = ald16(asrc + 2 * 32 + bq * 4);
        const v4f x3 = ald16(asrc + 3 * 32 + bq * 4);
        const v4f q0 = *(const v4f*)(wr0 + j * 32);
        const v4f q1 = *(const v4f*)(wr1 + j * 32);
        ac0 += q0[0] * x0 + q0[1] * x1 + q0[2] * x2 + q0[3] * x3;
        ac1 += q1[0] * x0 + q1[1] * x1 + q1[2] * x2 + q1[3] * x3;
      }
#pragma unroll
      for (int c = 0; c < 4; ++c) {
        float v0 = ac0[c], v1 = ac1[c];
        v0 += __shfl_xor(v0, 8);  v1 += __shfl_xor(v1, 8);
        v0 += __shfl_xor(v0, 16); v1 += __shfl_xor(v1, 16);
        v0 += __shfl_xor(v0, 32); v1 += __shfl_xor(v1, 32);
        ac0[c] = v0; ac1[c] = v1;
      }
      if (kl == 0) {
#pragma unroll
        for (int i = 0; i < 4; ++i) {
          arena[(kh * 8 + r0) * 32 + bq * 4 + i] = ac0[i];
          arena[(kh * 8 + r1) * 32 + bq * 4 + i] = ac1[i];
        }
      }
    }
    __syncthreads();
    if (t < 256) {
      const int r = t >> 5, b2 = t & 31;
      const int grow = (r >> 1) * ND + bid * 2 + (r & 1);
      arena[512 + r * 32 + b2] =
          arena[(0 * 8 + r) * 32 + b2] + arena[(1 * 8 + r) * 32 + b2]
        + p.bih1[grow] + p.bhh1[grow];
    }
    __syncthreads();
    if (t < 64) {
      const int dl = t >> 5, b2 = t & 31;
      const int idx = (bid * 2 + dl) * 32 + b2;
      const float gi = arena[512 + (0 + dl) * 32 + b2], gf = arena[512 + (2 + dl) * 32 + b2];
      const float gg = arena[512 + (4 + dl) * 32 + b2], go = arena[512 + (6 + dl) * 32 + b2];
      const float cn = sigm(gf) * p.c1[idx] + sigm(gi) * tanhf(gg);
      p.c1[idx] = cn;
      astf(&h1n[idx], sigm(go) * tanhf(cn));
    }
    gbar(p.bar, bid, ep++, false);

    // ===== P3: attention (blocks 224..255) ∥ pred-h1 (blocks 0..208) =====
    v4f pa[6];
#pragma unroll
    for (int r = 0; r < 6; ++r) pa[r] = (v4f){0.f, 0.f, 0.f, 0.f};
    if (bid >= ATT0) {
      const int b = bid - ATT0;
      float* hb  = arena;
      float* qs  = arena + 512;
      float* red = arena + 768;
      float* smx = arena + 1024;
      hb[t] = aldf(h1n + t * 32 + b);
      __syncthreads();
      const int kl = lane & 31, rh = lane >> 5;
      for (int pp = 0; pp < 16; ++pp) {
        const int r = w * 32 + pp * 2 + rh;
        const float* wq = p.Wq + (size_t)r * ND + kl * 4;
        float a = 0.f;
#pragma unroll
        for (int i = 0; i < 4; ++i) {
          const float4 w4 = *(const float4*)(wq + i * 128);
          const float4 h4 = *(const float4*)(hb + i * 128 + kl * 4);
          a += w4.x * h4.x + w4.y * h4.y + w4.z * h4.z + w4.w * h4.w;
        }
#pragma unroll
        for (int mk = 1; mk < 32; mk <<= 1) a += __shfl_xor(a, mk);
        if (kl == 0) qs[r] = (a + p.bq[r]) * 0.0625f;
      }
      __syncthreads();
      for (int pp = 0; pp < 13; ++pp) {
        const int s = pp * 16 + w * 2 + rh;
        float a = 0.f;
        if (s < NS) {
          const float* kr = p.keys + ((size_t)b * NS + s) * NK + kl * 4;
#pragma unroll
          for (int i = 0; i < 2; ++i) {
            const float4 k4 = *(const float4*)(kr + i * 128);
            const float4 q4 = *(const float4*)(qs + i * 128 + kl * 4);
            a += k4.x * q4.x + k4.y * q4.y + k4.z * q4.z + k4.w * q4.w;
          }
        }
#pragma unroll
        for (int mk = 1; mk < 32; mk <<= 1) a += __shfl_xor(a, mk);
        if (kl == 0 && s < NS) smx[s] = a;
      }
      __syncthreads();
      float e = -INFINITY;
      if (t < 256) { e = (t < NS) ? smx[t] : -INFINITY; red[t] = e; }
      __syncthreads();
      for (int off = 128; off; off >>= 1) {
        if (t < off) red[t] = fmaxf(red[t], red[t + off]);
        __syncthreads();
      }
      const float mx = red[0];
      __syncthreads();
      float a = 0.f;
      if (t < 256) { a = (t < NS) ? expf(e - mx) : 0.f; red[t] = a; }
      __syncthreads();
      for (int off = 128; off; off >>= 1) {
        if (t < off) red[t] += red[t + off];
        __syncthreads();
      }
      const float inv = 1.0f / red[0];
      if (t < 256) smx[t] = a * inv;
      __syncthreads();
      if (t < 256) {
        const float* vb = p.values + (size_t)b * NS * NK + t;
        float c0_ = 0.f, c1_ = 0.f, c2_ = 0.f, c3_ = 0.f;
        for (int s = 0; s < NS; s += 4) {
          c0_ += smx[s + 0] * vb[(size_t)(s + 0) * NK];
          c1_ += smx[s + 1] * vb[(size_t)(s + 1) * NK];
          c2_ += smx[s + 2] * vb[(size_t)(s + 2) * NK];
          c3_ += smx[s + 3] * vb[(size_t)(s + 3) * NK];
        }
        astf(&p.ctx[t * 32 + b], (c0_ + c1_) + (c2_ + c3_));
      }
    } else if (bid < NPRED) {
      const int bq = lane & 7, kl = lane >> 3;
      const int rbase = bid * 48 + w * 6;
      int rc[6];
#pragma unroll
      for (int r = 0; r < 6; ++r) rc[r] = (rbase + r < NV) ? (rbase + r) : (NV - 1);
#pragma unroll 2
      for (int j = 0; j < 16; ++j) {
        const int kk = j * 32 + kl * 4;
        const float* asrc = h1n + (size_t)kk * 32;
        const v4f x0 = ald16(asrc + 0 * 32 + bq * 4);
        const v4f x1 = ald16(asrc + 1 * 32 + bq * 4);
        const v4f x2 = ald16(asrc + 2 * 32 + bq * 4);
        const v4f x3 = ald16(asrc + 3 * 32 + bq * 4);
#pragma unroll
        for (int r = 0; r < 6; ++r) {
          const v4f q = *(const v4f*)(p.Wp + (size_t)rc[r] * 768 + kk);
          pa[r] += q[0] * x0 + q[1] * x1 + q[2] * x2 + q[3] * x3;
        }
      }
    }
    gbar(p.bar, bid, ep++, false);

    // ===== P4: pred-ctx part + reduce + out + argmax =====
    if (bid < NPRED) {
      const int bq = lane & 7, kl = lane >> 3;
      const int rbase = bid * 48 + w * 6;
      int rc[6];
#pragma unroll
      for (int r = 0; r < 6; ++r) rc[r] = (rbase + r < NV) ? (rbase + r) : (NV - 1);
#pragma unroll 2
      for (int j = 0; j < 8; ++j) {
        const int kk = j * 32 + kl * 4;
        const float* asrc = p.ctx + (size_t)kk * 32;
        const v4f x0 = ald16(asrc + 0 * 32 + bq * 4);
        const v4f x1 = ald16(asrc + 1 * 32 + bq * 4);
        const v4f x2 = ald16(asrc + 2 * 32 + bq * 4);
        const v4f x3 = ald16(asrc + 3 * 32 + bq * 4);
#pragma unroll
        for (int r = 0; r < 6; ++r) {
          const v4f q = *(const v4f*)(p.Wp + (size_t)rc[r] * 768 + 512 + kk);
          pa[r] += q[0] * x0 + q[1] * x1 + q[2] * x2 + q[3] * x3;
        }
      }
#pragma unroll
      for (int r = 0; r < 6; ++r) {
#pragma unroll
        for (int c = 0; c < 4; ++c) {
          float v = pa[r][c];
          v += __shfl_xor(v, 8);
          v += __shfl_xor(v, 16);
          v += __shfl_xor(v, 32);
          pa[r][c] = v;
        }
      }
      if (kl == 0) {
#pragma unroll
        for (int r = 0; r < 6; ++r)
#pragma unroll
          for (int i = 0; i < 4; ++i)
            arena[(w * 6 + r) * 32 + bq * 4 + i] = pa[r][i];
      }
      __syncthreads();
      if (t < 384) {
        const int b2 = t & 31, rg = t >> 5;
        const int vb = bid * 48 + rg * 4;
        u64 m = 0ull;
        if (vb + 3 < NV) {
          float4 v;
          float* vp = &v.x;
#pragma unroll
          for (int i = 0; i < 4; ++i) {
            const int row = rg * 4 + i;
            vp[i] = arena[row * 32 + b2] + p.bp[vb + i];
          }
          *(float4*)(p.out + ((size_t)b2 * NT + step) * NV + vb) = v;
          m = packmax(v.x, vb + 0);
          const u64 o1 = packmax(v.y, vb + 1); if (o1 > m) m = o1;
          const u64 o2 = packmax(v.z, vb + 2); if (o2 > m) m = o2;
          const u64 o3 = packmax(v.w, vb + 3); if (o3 > m) m = o3;
        }
        cand2[b2][rg] = m;
      }
      __syncthreads();
      if (t < 32) {
        u64 mm = cand2[t][0];
#pragma unroll
        for (int i = 1; i < 12; ++i) { const u64 o = cand2[t][i]; if (o > mm) mm = o; }
        (void)__hip_atomic_fetch_max(&p.amax[(bid & 7) * 32 + t], mm, __ATOMIC_RELAXED, SCOPE);
      }
    }
    gbar(p.bar, bid, ep++, false);
  }
}

// ---------------- host ----------------
extern "C" void kernel_launch(void* const* d_in, const int* in_sizes, int n_in,
                              void* d_out, int out_size, void* d_ws, size_t ws_size,
                              hipStream_t stream) {
  (void)in_sizes; (void)n_in; (void)out_size; (void)ws_size;
  Params prm;
  prm.x    = (const float*)d_in[0];
  prm.emb  = (const float*)d_in[1];
  prm.Wk   = (const float*)d_in[2];
  prm.bk   = (const float*)d_in[3];
  prm.Wv   = (const float*)d_in[4];
  prm.bv   = (const float*)d_in[5];
  prm.Wq   = (const float*)d_in[6];
  prm.bq   = (const float*)d_in[7];
  prm.Wp   = (const float*)d_in[8];
  prm.bp   = (const float*)d_in[9];
  prm.Wih0 = (const float*)d_in[10];
  prm.Whh0 = (const float*)d_in[11];
  prm.bih0 = (const float*)d_in[12];
  prm.bhh0 = (const float*)d_in[13];
  prm.Wih1 = (const float*)d_in[14];
  prm.Whh1 = (const float*)d_in[15];
  prm.bih1 = (const float*)d_in[16];
  prm.bhh1 = (const float*)d_in[17];
  prm.out  = (float*)d_out;

  float* ws = (float*)d_ws;
  prm.keys   = ws;
  prm.values = prm.keys + 1605632;
  prm.h0t    = prm.values + 1605632;
  prm.h1t    = prm.h0t + 32768;
  prm.c0     = prm.h1t + 32768;
  prm.c1     = prm.c0 + 16384;
  prm.ctx    = prm.c1 + 16384;
  prm.amax   = (u64*)(prm.ctx + 8192);
  prm.bar    = (unsigned*)(prm.amax + 256);

  const int LDS = (10240 + 8192 + 4096) * 4;  // 90,112 B dynamic
  (void)hipFuncSetAttribute((const void*)k_all, hipFuncAttributeMaxDynamicSharedMemorySize, LDS);

  k_zbar<<<4, 256, 0, stream>>>(prm.bar);
  void* args[] = { &prm };
  (void)hipLaunchCooperativeKernel((const void*)k_all, dim3(NBLK), dim3(NTHR), args,
                                   (unsigned)LDS, stream);
}